// Round 4
// baseline (816.079 us; speedup 1.0000x reference)
//
#include <hip/hip_runtime.h>
#include <cstdint>

// Zoom-aware MSA, MI355X/gfx950.
// Round-4: runtime dtype sniff. Three rounds of NaN with verified index math
// + guarded softmax => input bytes are not bf16 (fp32 low-halves read as bf16
// give ~0.4% Inf/NaN => NaN via PV). A sniff kernel detects fp32 vs bf16 from
// q's bit patterns (fp32 mantissa halves are uniform => bf16-exponent >= 0xC0
// appears w.p. ~25%/short; bf16 N(0,1) never). All kernels branch uniformly
// on the flag: inputs converted on load; final store dtype follows the flag.
// Intermediates always bf16 in d_ws (flag + 4 x G x 2MB buffers, adaptive G).

#define SQ   1024
#define HID  1024
#define SCALE 0.125f

typedef __attribute__((ext_vector_type(8))) __bf16 bf16x8;
typedef __attribute__((ext_vector_type(8))) unsigned short ushort8;
typedef __attribute__((ext_vector_type(4))) float  floatx4;
typedef __attribute__((ext_vector_type(2))) float  floatx2;

__device__ __forceinline__ float b2f(unsigned short x) {
    return __builtin_bit_cast(float, (uint32_t)x << 16);
}
__device__ __forceinline__ unsigned short f2bf(float f) {
    uint32_t u = __builtin_bit_cast(uint32_t, f);
    u += 0x7fffu + ((u >> 16) & 1u);          // round-to-nearest-even
    return (unsigned short)(u >> 16);
}

// 8 consecutive elements starting at element index ei, as bf16x8.
__device__ __forceinline__ bf16x8 load8(const void* base, size_t ei, bool f32) {
    if (f32) {
        const float* p = (const float*)base + ei;
        const floatx4 u = *(const floatx4*)p;
        const floatx4 v = *(const floatx4*)(p + 4);
        ushort8 r;
        r[0] = f2bf(u[0]); r[1] = f2bf(u[1]); r[2] = f2bf(u[2]); r[3] = f2bf(u[3]);
        r[4] = f2bf(v[0]); r[5] = f2bf(v[1]); r[6] = f2bf(v[2]); r[7] = f2bf(v[3]);
        return __builtin_bit_cast(bf16x8, r);
    }
    return *(const bf16x8*)((const short*)base + ei);
}
__device__ __forceinline__ float loadS(const void* base, size_t ei, bool f32) {
    return f32 ? ((const float*)base)[ei] : b2f(((const unsigned short*)base)[ei]);
}
__device__ __forceinline__ floatx2 loadPair(const void* base, size_t ei, bool f32) {
    if (f32) return *(const floatx2*)((const float*)base + ei);
    const uint32_t u = *(const uint32_t*)((const unsigned short*)base + ei);
    floatx2 r; r[0] = b2f((unsigned short)(u & 0xffffu)); r[1] = b2f((unsigned short)(u >> 16));
    return r;
}

// Detect fp32 vs bf16 storage of q. fp32 N(0,1): even shorts are uniform
// mantissa bits -> bf16-exponent field >= 0xC0 with p~.25. bf16 N(0,1): never.
__global__ void sniff(const unsigned short* __restrict__ q, int* __restrict__ flag) {
    __shared__ int s;
    if (threadIdx.x == 0) s = 0;
    __syncthreads();
    const uint4 d = ((const uint4*)q)[threadIdx.x];       // 8 shorts
    const uint32_t wds[4] = {d.x, d.y, d.z, d.w};
    bool hit = false;
#pragma unroll
    for (int i = 0; i < 4; ++i) {
        const uint32_t lo = wds[i] & 0xffffu, hi = wds[i] >> 16;
        if (((lo >> 7) & 0xffu) >= 0xC0u || ((hi >> 7) & 0xffu) >= 0xC0u) hit = true;
    }
    if (hit) s = 1;                                        // same-value race ok
    __syncthreads();
    if (threadIdx.x == 0) *flag = s;
}

// C = A[M,1024] @ Bw[1024,1024]^T + bias, fp32 accum. A dtype: bf16 if
// !aPerFlag else per flag; Bw/bias per flag; store fp32 iff finalOut && flag.
// TRANS: store as [row>>10][n][row&1023] (bf16 only).
template <bool TRANS>
__global__ __launch_bounds__(256) void gemm_bt(
    const void* __restrict__ A, size_t aOff, const void* __restrict__ Bw,
    const void* __restrict__ bias, void* __restrict__ C, size_t cOff,
    const int* __restrict__ flagp, int aPerFlag, int finalOut)
{
    __shared__ __align__(16) short As[4096];   // region r: rows 16r+c, k=quad*8
    __shared__ __align__(16) short Bs[4096];

    const bool f32  = *flagp != 0;
    const bool af32 = aPerFlag && f32;

    const int tid = threadIdx.x;
    const int w = tid >> 6, lane = tid & 63;
    const int quad = lane >> 4, c = lane & 15;
    const int bm = blockIdx.y, bn = blockIdx.x;
    const int wr = w >> 1, wc = w & 1;

    size_t a0 = aOff + (size_t)(bm * 128 + w * 16 + c) * HID + quad * 8;
    size_t a1 = aOff + (size_t)(bm * 128 + (w + 4) * 16 + c) * HID + quad * 8;
    size_t b0 = (size_t)(bn * 128 + w * 16 + c) * HID + quad * 8;
    size_t b1 = (size_t)(bn * 128 + (w + 4) * 16 + c) * HID + quad * 8;

    bf16x8 va0 = load8(A, a0, af32), va1 = load8(A, a1, af32);
    bf16x8 vb0 = load8(Bw, b0, f32), vb1 = load8(Bw, b1, f32);

    floatx4 acc[4][4] = {};

    for (int kt = 0; kt < 32; ++kt) {
        __syncthreads();
        *(bf16x8*)(As + w * 512 + lane * 8)       = va0;
        *(bf16x8*)(As + (w + 4) * 512 + lane * 8) = va1;
        *(bf16x8*)(Bs + w * 512 + lane * 8)       = vb0;
        *(bf16x8*)(Bs + (w + 4) * 512 + lane * 8) = vb1;
        __syncthreads();

        if (kt < 31) {                           // prefetch next tile
            a0 += 32; a1 += 32; b0 += 32; b1 += 32;
            va0 = load8(A, a0, af32); va1 = load8(A, a1, af32);
            vb0 = load8(Bw, b0, f32); vb1 = load8(Bw, b1, f32);
        }

        bf16x8 a[4], b[4];
#pragma unroll
        for (int i = 0; i < 4; ++i)
            a[i] = *(const bf16x8*)(As + (wr * 4 + i) * 512 + lane * 8);
#pragma unroll
        for (int j = 0; j < 4; ++j)
            b[j] = *(const bf16x8*)(Bs + (wc * 4 + j) * 512 + lane * 8);
#pragma unroll
        for (int i = 0; i < 4; ++i)
#pragma unroll
            for (int j = 0; j < 4; ++j)
                acc[i][j] = __builtin_amdgcn_mfma_f32_16x16x32_bf16(a[i], b[j], acc[i][j], 0, 0, 0);
    }

    float bsv[4];
#pragma unroll
    for (int j = 0; j < 4; ++j)
        bsv[j] = loadS(bias, bn * 128 + wc * 64 + j * 16 + c, f32);

    const bool of32 = finalOut && f32;
#pragma unroll
    for (int i = 0; i < 4; ++i) {
#pragma unroll
        for (int j = 0; j < 4; ++j) {
            const int n = bn * 128 + wc * 64 + j * 16 + c;
#pragma unroll
            for (int r = 0; r < 4; ++r) {
                const int row = bm * 128 + wr * 64 + i * 16 + quad * 4 + r;  // C/D: row=quad*4+reg, col=lane&15
                const float val = acc[i][j][r] + bsv[j];
                size_t idx;
                if (TRANS) idx = ((size_t)(row >> 10) * HID + n) * SQ + (row & 1023);
                else       idx = (size_t)row * HID + n;
                if (of32) ((float*)C)[cOff + idx] = val;
                else      ((unsigned short*)C)[cOff + idx] = f2bf(val);
            }
        }
    }
}

// Fused attention. Block = 128 q-rows of one (bl, h); wave = 32 q-rows;
// 32-key tiles; score frag kb holds keys 2n+kb (even/odd permutation).
// qh/kh/vht: bf16 ws buffers. abias/zb: per flag. aout: bf16 ws.
__global__ __launch_bounds__(256) void attn(
    const short* __restrict__ qh, const short* __restrict__ kh,
    const short* __restrict__ vht, const void* __restrict__ abias,
    const void* __restrict__ zb, short* __restrict__ aout,
    const int* __restrict__ flagp, int b0)
{
    __shared__ __align__(16) short Kf[2048];
    __shared__ __align__(16) short Vf[2048];
    __shared__ __align__(16) short Ps[4][1536];
    __shared__ float Zs[1152];

    const bool f32 = *flagp != 0;
    const int tid = threadIdx.x;
    const int w = tid >> 6, lane = tid & 63;
    const int quad = lane >> 4, c = lane & 15;
    const int qb = blockIdx.x, h = blockIdx.y, bl = blockIdx.z;
    const int b = b0 + bl;

    for (int j = tid; j < 1151; j += 256)
        Zs[j] = loadS(zb, qb * 128 + j, f32);

    const size_t blS = (size_t)bl * SQ;

    bf16x8 qa[2][2];     // A-frag: A[m=lane&15][k=quad*8+j]
#pragma unroll
    for (int m = 0; m < 2; ++m)
#pragma unroll
        for (int half = 0; half < 2; ++half)
            qa[m][half] = *(const bf16x8*)(qh + (blS + qb * 128 + w * 32 + m * 16 + c) * HID
                                               + h * 64 + half * 32 + quad * 8);

    const short* kg = kh  + (blS + 2 * c + (w & 1)) * HID + h * 64 + (w >> 1) * 32 + quad * 8;
    const short* vg = vht + ((size_t)bl * HID + h * 64 + w * 16 + c) * SQ + quad * 8;
    const size_t bge = ((size_t)b * SQ + qb * 128 + w * 32 + quad * 4) * SQ + 2 * c;

    bf16x8 kv = *(const bf16x8*)kg;   // wave w: K region (half=w>>1, kb=w&1)
    bf16x8 vv = *(const bf16x8*)vg;   // V region dt=w

    floatx4 o[2][4] = {};
    float sume[2][4] = {};

    for (int kt = 0; kt < 32; ++kt) {
        __syncthreads();
        *(bf16x8*)(Kf + w * 512 + lane * 8) = kv;
        *(bf16x8*)(Vf + w * 512 + lane * 8) = vv;
        __syncthreads();

        if (kt < 31) {
            kg += 32 * HID; vg += 32;
            kv = *(const bf16x8*)kg;
            vv = *(const bf16x8*)vg;
        }

        bf16x8 kf[2][2];
#pragma unroll
        for (int half = 0; half < 2; ++half)
#pragma unroll
            for (int kb = 0; kb < 2; ++kb)
                kf[half][kb] = *(const bf16x8*)(Kf + (half * 2 + kb) * 512 + lane * 8);

        floatx4 sc[2][2] = {};
#pragma unroll
        for (int m = 0; m < 2; ++m)
#pragma unroll
            for (int kb = 0; kb < 2; ++kb) {
                sc[m][kb] = __builtin_amdgcn_mfma_f32_16x16x32_bf16(qa[m][0], kf[0][kb], sc[m][kb], 0, 0, 0);
                sc[m][kb] = __builtin_amdgcn_mfma_f32_16x16x32_bf16(qa[m][1], kf[1][kb], sc[m][kb], 0, 0, 0);
            }

        const int k0 = kt * 32 + 2 * c;
#pragma unroll
        for (int m = 0; m < 2; ++m) {
#pragma unroll
            for (int r = 0; r < 4; ++r) {
                const int lrq = w * 32 + m * 16 + quad * 4 + r;
                const int zj = lrq + 1023 - k0;                  // in [1,1150]
                const float z0 = Zs[zj], z1 = Zs[zj - 1];
                const floatx2 bp = loadPair(abias, bge + (size_t)(m * 16 + r) * SQ + kt * 32, f32);
                const float s0 = fminf(sc[m][0][r] * SCALE + z0 + bp[0], 25.0f);
                const float s1 = fminf(sc[m][1][r] * SCALE + z1 + bp[1], 25.0f);
                const float e0 = __expf(s0), e1 = __expf(s1);
                sume[m][r] += e0 + e1;
                const uint32_t pp = (uint32_t)f2bf(e0) | ((uint32_t)f2bf(e1) << 16);
                *(uint32_t*)((unsigned short*)&Ps[w][0] + (m * 16 + quad * 4 + r) * 48 + 2 * c) = pp;
            }
        }

        bf16x8 ap[2];
#pragma unroll
        for (int m = 0; m < 2; ++m)
            ap[m] = *(const bf16x8*)(&Ps[w][0] + (m * 16 + c) * 48 + quad * 8);
#pragma unroll
        for (int dt = 0; dt < 4; ++dt) {
            const bf16x8 vf = *(const bf16x8*)(Vf + dt * 512 + lane * 8);
#pragma unroll
            for (int m = 0; m < 2; ++m)
                o[m][dt] = __builtin_amdgcn_mfma_f32_16x16x32_bf16(ap[m], vf, o[m][dt], 0, 0, 0);
        }
    }

#pragma unroll
    for (int m = 0; m < 2; ++m)
#pragma unroll
        for (int r = 0; r < 4; ++r) {
            float s = sume[m][r];
            s += __shfl_xor(s, 1);
            s += __shfl_xor(s, 2);
            s += __shfl_xor(s, 4);
            s += __shfl_xor(s, 8);
            sume[m][r] = 1.0f / fmaxf(s, 1e-30f);
        }

#pragma unroll
    for (int m = 0; m < 2; ++m)
#pragma unroll
        for (int dt = 0; dt < 4; ++dt)
#pragma unroll
            for (int r = 0; r < 4; ++r) {
                const size_t row = blS + qb * 128 + w * 32 + m * 16 + quad * 4 + r;
                ((unsigned short*)aout)[row * HID + h * 64 + dt * 16 + c] =
                    f2bf(o[m][dt][r] * sume[m][r]);
            }
}

extern "C" void kernel_launch(void* const* d_in, const int* in_sizes, int n_in,
                              void* d_out, int out_size, void* d_ws, size_t ws_size,
                              hipStream_t stream) {
    const void* q  = d_in[0];
    const void* k  = d_in[1];
    const void* v  = d_in[2];
    const void* ab = d_in[3];
    const void* Wq = d_in[4];  const void* bq = d_in[5];
    const void* Wk = d_in[6];  const void* bk = d_in[7];
    const void* Wv = d_in[8];  const void* bv = d_in[9];
    const void* Wo = d_in[10]; const void* bo = d_in[11];
    const void* zb = d_in[12];

    const size_t perB = (size_t)SQ * HID;
    int G = 8;
    while (G > 1 && 256 + 8ull * G * perB > ws_size) G >>= 1;

    int*   flagp = (int*)d_ws;
    short* qh    = (short*)((char*)d_ws + 256);
    short* khp   = qh  + (size_t)G * perB;
    short* vht   = khp + (size_t)G * perB;
    short* ao    = vht + (size_t)G * perB;

    const dim3 bt(256);
    const dim3 gg(8, G * 8);
    const int ngroups = 8 / G;

    sniff<<<1, 256, 0, stream>>>((const unsigned short*)q, flagp);

    for (int g = 0; g < ngroups; ++g) {
        const size_t off = (size_t)g * G * perB;
        gemm_bt<false><<<gg, bt, 0, stream>>>(q, off, Wq, bq, qh,  0, flagp, 1, 0);
        gemm_bt<false><<<gg, bt, 0, stream>>>(k, off, Wk, bk, khp, 0, flagp, 1, 0);
        gemm_bt<true ><<<gg, bt, 0, stream>>>(v, off, Wv, bv, vht, 0, flagp, 1, 0);
        attn<<<dim3(8, 16, G), bt, 0, stream>>>(qh, khp, vht, ab, zb, ao, flagp, g * G);
        gemm_bt<false><<<gg, bt, 0, stream>>>(ao, 0, Wo, bo, d_out, off, flagp, 0, 1);
    }
}

// Round 5
// 535.365 us; speedup vs baseline: 1.5243x; 1.5243x over previous
//
#include <hip/hip_runtime.h>
#include <cstdint>

// Zoom-aware MSA, MI355X/gfx950. Inputs fp32 (confirmed R4), output fp32.
// R5: (1) pre-convert W* and attn_bias fp32->bf16 once (memory-bound passes);
// (2) GEMMs: B-operand pure bf16, A converts in-loop only for the 3 input
// projections, O-projection pure bf16 -> halves the R4 conversion VALU;
// (3) attn: 64-key tiles (16 iters, half the barriers), bf16 bias loads
// (4B/lane), no clamp. Explicit LDS staging + reg prefetch throughout
// (proven correct in R3/R4; GLDS deferred).

#define SQ   1024
#define HID  1024
#define SCALE 0.125f

typedef __attribute__((ext_vector_type(8))) __bf16 bf16x8;
typedef __attribute__((ext_vector_type(8))) unsigned short ushort8;
typedef __attribute__((ext_vector_type(4))) float  floatx4;

__device__ __forceinline__ float b2f(unsigned short x) {
    return __builtin_bit_cast(float, (uint32_t)x << 16);
}
__device__ __forceinline__ unsigned short f2bf(float f) {
    uint32_t u = __builtin_bit_cast(uint32_t, f);
    u += 0x7fffu + ((u >> 16) & 1u);          // RTNE
    return (unsigned short)(u >> 16);
}

// 8 consecutive fp32 elements -> bf16x8 (in-loop A conversion).
__device__ __forceinline__ bf16x8 cvt8(const float* p) {
    const floatx4 u = *(const floatx4*)p;
    const floatx4 v = *(const floatx4*)(p + 4);
    ushort8 r;
    r[0] = f2bf(u[0]); r[1] = f2bf(u[1]); r[2] = f2bf(u[2]); r[3] = f2bf(u[3]);
    r[4] = f2bf(v[0]); r[5] = f2bf(v[1]); r[6] = f2bf(v[2]); r[7] = f2bf(v[3]);
    return __builtin_bit_cast(bf16x8, r);
}

// fp32 -> bf16 elementwise, n % 4 == 0.
__global__ void cvt(const float* __restrict__ s, unsigned short* __restrict__ d, int n4) {
    const int i = blockIdx.x * blockDim.x + threadIdx.x;
    if (i >= n4) return;
    const floatx4 v = *(const floatx4*)(s + 4 * (size_t)i);
    uint32_t lo = (uint32_t)f2bf(v[0]) | ((uint32_t)f2bf(v[1]) << 16);
    uint32_t hi = (uint32_t)f2bf(v[2]) | ((uint32_t)f2bf(v[3]) << 16);
    ((uint2*)d)[i] = make_uint2(lo, hi);
}

// C = A[M,1024] @ Bw[1024,1024]^T + bias[1024]; fp32 accum.
// A: fp32 (AF32) or bf16; Bw: bf16 (pre-converted); bias: fp32.
// outF32: store fp32 (final O-proj) else bf16.
// TRANS: store as [row>>10][n][row&1023] (bf16 only; V projection).
template <bool AF32, bool TRANS>
__global__ __launch_bounds__(256) void gemm_bt(
    const void* __restrict__ A, size_t aOff, const short* __restrict__ Bw,
    const float* __restrict__ bias, void* __restrict__ C, size_t cOff, int outF32)
{
    __shared__ __align__(16) short As[4096];   // region r: rows 16r+c, k=quad*8
    __shared__ __align__(16) short Bs[4096];

    const int tid = threadIdx.x;
    const int w = tid >> 6, lane = tid & 63;
    const int quad = lane >> 4, c = lane & 15;
    const int bm = blockIdx.y, bn = blockIdx.x;
    const int wr = w >> 1, wc = w & 1;

    size_t a0 = aOff + (size_t)(bm * 128 + w * 16 + c) * HID + quad * 8;
    size_t a1 = aOff + (size_t)(bm * 128 + (w + 4) * 16 + c) * HID + quad * 8;
    const short* bg0 = Bw + (size_t)(bn * 128 + w * 16 + c) * HID + quad * 8;
    const short* bg1 = Bw + (size_t)(bn * 128 + (w + 4) * 16 + c) * HID + quad * 8;

    bf16x8 va0 = AF32 ? cvt8((const float*)A + a0) : *(const bf16x8*)((const short*)A + a0);
    bf16x8 va1 = AF32 ? cvt8((const float*)A + a1) : *(const bf16x8*)((const short*)A + a1);
    bf16x8 vb0 = *(const bf16x8*)bg0;
    bf16x8 vb1 = *(const bf16x8*)bg1;

    floatx4 acc[4][4] = {};

    for (int kt = 0; kt < 32; ++kt) {
        __syncthreads();
        *(bf16x8*)(As + w * 512 + lane * 8)       = va0;
        *(bf16x8*)(As + (w + 4) * 512 + lane * 8) = va1;
        *(bf16x8*)(Bs + w * 512 + lane * 8)       = vb0;
        *(bf16x8*)(Bs + (w + 4) * 512 + lane * 8) = vb1;
        __syncthreads();

        if (kt < 31) {                           // prefetch next tile
            a0 += 32; a1 += 32; bg0 += 32; bg1 += 32;
            va0 = AF32 ? cvt8((const float*)A + a0) : *(const bf16x8*)((const short*)A + a0);
            va1 = AF32 ? cvt8((const float*)A + a1) : *(const bf16x8*)((const short*)A + a1);
            vb0 = *(const bf16x8*)bg0;
            vb1 = *(const bf16x8*)bg1;
        }

        bf16x8 a[4], b[4];
#pragma unroll
        for (int i = 0; i < 4; ++i)
            a[i] = *(const bf16x8*)(As + (wr * 4 + i) * 512 + lane * 8);
#pragma unroll
        for (int j = 0; j < 4; ++j)
            b[j] = *(const bf16x8*)(Bs + (wc * 4 + j) * 512 + lane * 8);
#pragma unroll
        for (int i = 0; i < 4; ++i)
#pragma unroll
            for (int j = 0; j < 4; ++j)
                acc[i][j] = __builtin_amdgcn_mfma_f32_16x16x32_bf16(a[i], b[j], acc[i][j], 0, 0, 0);
    }

    float bsv[4];
#pragma unroll
    for (int j = 0; j < 4; ++j)
        bsv[j] = bias[bn * 128 + wc * 64 + j * 16 + c];

#pragma unroll
    for (int i = 0; i < 4; ++i) {
#pragma unroll
        for (int j = 0; j < 4; ++j) {
            const int n = bn * 128 + wc * 64 + j * 16 + c;
#pragma unroll
            for (int r = 0; r < 4; ++r) {
                const int row = bm * 128 + wr * 64 + i * 16 + quad * 4 + r;  // C/D: row=quad*4+reg, col=c
                const float val = acc[i][j][r] + bsv[j];
                size_t idx;
                if (TRANS) idx = ((size_t)(row >> 10) * HID + n) * SQ + (row & 1023);
                else       idx = (size_t)row * HID + n;
                if (outF32) ((float*)C)[cOff + idx] = val;
                else        ((unsigned short*)C)[cOff + idx] = f2bf(val);
            }
        }
    }
}

// Fused attention, 64-key tiles. Block = 128 q-rows of (bl, h); wave = 32
// q-rows. Score frag kb holds keys 2n+kb (even/odd permutation) so each
// lane's score pair {2c,2c+1} is one b32 bf16-pair bias load / Ps write.
__global__ __launch_bounds__(256) void attn(
    const short* __restrict__ qh, const short* __restrict__ kh,
    const short* __restrict__ vht, const unsigned short* __restrict__ abc,
    const float* __restrict__ zbf, short* __restrict__ aout, int b0)
{
    __shared__ __align__(16) short Kf[4096];     // region sub*4+half*2+kb
    __shared__ __align__(16) short Vf[4096];     // region sub*4+dt
    __shared__ __align__(16) short Ps[4][2304];  // per-wave 32 x 72-stride
    __shared__ float Zs[1152];

    const int tid = threadIdx.x;
    const int w = tid >> 6, lane = tid & 63;
    const int quad = lane >> 4, c = lane & 15;
    const int qb = blockIdx.x, h = blockIdx.y, bl = blockIdx.z;
    const int b = b0 + bl;

    for (int j = tid; j < 1151; j += 256)
        Zs[j] = zbf[qb * 128 + j];

    const size_t blS = (size_t)bl * SQ;

    bf16x8 qa[2][2];     // A-frag: A[m=lane&15][k=quad*8+j]
#pragma unroll
    for (int m = 0; m < 2; ++m)
#pragma unroll
        for (int half = 0; half < 2; ++half)
            qa[m][half] = *(const bf16x8*)(qh + (blS + qb * 128 + w * 32 + m * 16 + c) * HID
                                               + h * 64 + half * 32 + quad * 8);

    // wave w stages: K regions (sub,half=w>>1,kb=w&1), V regions (sub,dt=w)
    const short* kg = kh  + (blS + 2 * c + (w & 1)) * HID + h * 64 + (w >> 1) * 32 + quad * 8;
    const short* vg = vht + ((size_t)bl * HID + h * 64 + w * 16 + c) * SQ + quad * 8;
    const size_t bge = ((size_t)b * SQ + qb * 128 + w * 32 + quad * 4) * SQ;

    bf16x8 kv0 = *(const bf16x8*)kg, kv1 = *(const bf16x8*)(kg + 32 * HID);
    bf16x8 vv0 = *(const bf16x8*)vg, vv1 = *(const bf16x8*)(vg + 32);

    floatx4 o[2][4] = {};
    float sume[2][4] = {};

    for (int kt = 0; kt < 16; ++kt) {
        __syncthreads();
        *(bf16x8*)(Kf + w * 512 + lane * 8)       = kv0;
        *(bf16x8*)(Kf + (w + 4) * 512 + lane * 8) = kv1;
        *(bf16x8*)(Vf + w * 512 + lane * 8)       = vv0;
        *(bf16x8*)(Vf + (w + 4) * 512 + lane * 8) = vv1;
        __syncthreads();

        if (kt < 15) {                            // prefetch next 64-key tile
            kg += 64 * HID; vg += 64;
            kv0 = *(const bf16x8*)kg; kv1 = *(const bf16x8*)(kg + 32 * HID);
            vv0 = *(const bf16x8*)vg; vv1 = *(const bf16x8*)(vg + 32);
        }

        floatx4 sc[2][2][2] = {};                 // [m][sub][kb]
#pragma unroll
        for (int sub = 0; sub < 2; ++sub) {
            bf16x8 kf[2][2];
#pragma unroll
            for (int half = 0; half < 2; ++half)
#pragma unroll
                for (int kb = 0; kb < 2; ++kb)
                    kf[half][kb] = *(const bf16x8*)(Kf + (sub * 4 + half * 2 + kb) * 512 + lane * 8);
#pragma unroll
            for (int m = 0; m < 2; ++m)
#pragma unroll
                for (int kb = 0; kb < 2; ++kb) {
                    sc[m][sub][kb] = __builtin_amdgcn_mfma_f32_16x16x32_bf16(qa[m][0], kf[0][kb], sc[m][sub][kb], 0, 0, 0);
                    sc[m][sub][kb] = __builtin_amdgcn_mfma_f32_16x16x32_bf16(qa[m][1], kf[1][kb], sc[m][sub][kb], 0, 0, 0);
                }
        }

        const int k0 = kt * 64;
#pragma unroll
        for (int m = 0; m < 2; ++m) {
#pragma unroll
            for (int r = 0; r < 4; ++r) {
                const int lrq = w * 32 + m * 16 + quad * 4 + r;
                const int tb = lrq + 1023 - k0;                   // Zs idx = tb - local key
                const size_t brow = bge + (size_t)(m * 16 + r) * SQ + k0;
#pragma unroll
                for (int sub = 0; sub < 2; ++sub) {
                    const int kl = sub * 32 + 2 * c;
                    const uint32_t bp = *(const uint32_t*)(abc + brow + kl);
                    const float z0 = Zs[tb - kl], z1 = Zs[tb - kl - 1];
                    const float s0 = sc[m][sub][0][r] * SCALE + z0 + b2f((unsigned short)(bp & 0xffffu));
                    const float s1 = sc[m][sub][1][r] * SCALE + z1
                                   + __builtin_bit_cast(float, bp & 0xffff0000u);
                    const float e0 = __expf(s0), e1 = __expf(s1);
                    sume[m][r] += e0 + e1;
                    const uint32_t pp = (uint32_t)f2bf(e0) | ((uint32_t)f2bf(e1) << 16);
                    *(uint32_t*)(&Ps[w][0] + (m * 16 + quad * 4 + r) * 72 + kl) = pp;
                }
            }
        }

#pragma unroll
        for (int sub = 0; sub < 2; ++sub) {
            bf16x8 ap[2];
#pragma unroll
            for (int m = 0; m < 2; ++m)
                ap[m] = *(const bf16x8*)(&Ps[w][0] + (m * 16 + c) * 72 + sub * 32 + quad * 8);
#pragma unroll
            for (int dt = 0; dt < 4; ++dt) {
                const bf16x8 vf = *(const bf16x8*)(Vf + (sub * 4 + dt) * 512 + lane * 8);
#pragma unroll
                for (int m = 0; m < 2; ++m)
                    o[m][dt] = __builtin_amdgcn_mfma_f32_16x16x32_bf16(ap[m], vf, o[m][dt], 0, 0, 0);
            }
        }
    }

#pragma unroll
    for (int m = 0; m < 2; ++m)
#pragma unroll
        for (int r = 0; r < 4; ++r) {
            float s = sume[m][r];
            s += __shfl_xor(s, 1);
            s += __shfl_xor(s, 2);
            s += __shfl_xor(s, 4);
            s += __shfl_xor(s, 8);
            sume[m][r] = 1.0f / s;
        }

#pragma unroll
    for (int m = 0; m < 2; ++m)
#pragma unroll
        for (int dt = 0; dt < 4; ++dt)
#pragma unroll
            for (int r = 0; r < 4; ++r) {
                const size_t row = blS + qb * 128 + w * 32 + m * 16 + quad * 4 + r;
                ((unsigned short*)aout)[row * HID + h * 64 + dt * 16 + c] =
                    f2bf(o[m][dt][r] * sume[m][r]);
            }
}

extern "C" void kernel_launch(void* const* d_in, const int* in_sizes, int n_in,
                              void* d_out, int out_size, void* d_ws, size_t ws_size,
                              hipStream_t stream) {
    const float* q  = (const float*)d_in[0];
    const float* k  = (const float*)d_in[1];
    const float* v  = (const float*)d_in[2];
    const float* ab = (const float*)d_in[3];
    const float* Wq = (const float*)d_in[4];  const float* bq = (const float*)d_in[5];
    const float* Wk = (const float*)d_in[6];  const float* bk = (const float*)d_in[7];
    const float* Wv = (const float*)d_in[8];  const float* bv = (const float*)d_in[9];
    const float* Wo = (const float*)d_in[10]; const float* bo = (const float*)d_in[11];
    const float* zb = (const float*)d_in[12];

    const size_t perB = (size_t)SQ * HID;            // 1M elems per batch
    const size_t WN   = (size_t)HID * HID;           // 1M elems per weight

    // ws: 4 bf16 weights (8MB) + bf16 attn_bias (16MB) + 4 x G x 2MB.
    int G = 8;
    while (G > 1 && 24ull * 1024 * 1024 + 8ull * G * perB > ws_size) G >>= 1;

    unsigned short* Wqc = (unsigned short*)d_ws;
    unsigned short* Wkc = Wqc + WN;
    unsigned short* Wvc = Wkc + WN;
    unsigned short* Woc = Wvc + WN;
    unsigned short* abc = Woc + WN;                  // 8M elems
    short* qh  = (short*)(abc + 8 * perB);
    short* khp = qh  + (size_t)G * perB;
    short* vht = khp + (size_t)G * perB;
    short* ao  = vht + (size_t)G * perB;

    const dim3 bt(256);
    const dim3 gg(8, G * 8);
    const int ngroups = 8 / G;

    cvt<<<(WN / 4 + 255) / 256, 256, 0, stream>>>(Wq, Wqc, WN / 4);
    cvt<<<(WN / 4 + 255) / 256, 256, 0, stream>>>(Wk, Wkc, WN / 4);
    cvt<<<(WN / 4 + 255) / 256, 256, 0, stream>>>(Wv, Wvc, WN / 4);
    cvt<<<(WN / 4 + 255) / 256, 256, 0, stream>>>(Wo, Woc, WN / 4);
    cvt<<<(8 * perB / 4 + 255) / 256, 256, 0, stream>>>(ab, abc, 8 * perB / 4);

    for (int g = 0; g < ngroups; ++g) {
        const size_t off = (size_t)g * G * perB;
        gemm_bt<true,  false><<<gg, bt, 0, stream>>>(q, off, (short*)Wqc, bq, qh,  0, 0);
        gemm_bt<true,  false><<<gg, bt, 0, stream>>>(k, off, (short*)Wkc, bk, khp, 0, 0);
        gemm_bt<true,  true ><<<gg, bt, 0, stream>>>(v, off, (short*)Wvc, bv, vht, 0, 0);
        attn<<<dim3(8, 16, G), bt, 0, stream>>>(qh, khp, vht, abc, zb, ao, g * G);
        gemm_bt<false, false><<<gg, bt, 0, stream>>>(ao, 0, (short*)Woc, bo, d_out, off, 1);
    }
}